// Round 1
// baseline (1061.273 us; speedup 1.0000x reference)
//
#include <hip/hip_runtime.h>
#include <math.h>

#define NT 256
constexpr int B_   = 8192;
constexpr int N_   = 100;
constexpr int E_   = 1600;
constexpr int EMB  = 5;
constexpr int XDIM = 500;    // N_*EMB
constexpr int DDIM = 2600;   // 50*52
constexpr int KTOT = 3100;   // XDIM + DDIM
constexpr int H1 = 128, H2 = 128, H3 = 64, HO = 2;

__device__ __forceinline__ float leaky(float v) { return v > 0.f ? v : 0.01f * v; }
__device__ __forceinline__ float sigm(float v)  { return 1.f / (1.f + __expf(-v)); }

// ---------------- Kernel 1: fused 3-layer gated RGCN, one block per batch b ----
__global__ __launch_bounds__(NT) void gnn_kernel(
    const float* __restrict__ data, const int* __restrict__ src, const int* __restrict__ dst,
    const float* __restrict__ W0, const float* __restrict__ b0, const float* __restrict__ G0, const float* __restrict__ gb0,
    const float* __restrict__ W1, const float* __restrict__ b1, const float* __restrict__ G1, const float* __restrict__ gb1,
    const float* __restrict__ W2, const float* __restrict__ b2, const float* __restrict__ G2, const float* __restrict__ gb2,
    float* __restrict__ xw)
{
  __shared__ float h[XDIM];
  __shared__ float agg[XDIM];
  __shared__ float h2s[XDIM];
  __shared__ int ssrc[E_];
  __shared__ int sdst[E_];
  const int t = threadIdx.x;
  const int b = blockIdx.x;

  for (int e = t; e < E_; e += NT) { ssrc[e] = src[e]; sdst[e] = dst[e]; }
  if (t < N_) { h[t] = data[(size_t)b * N_ + t]; agg[t] = 0.f; }
  __syncthreads();

  // ---- layer 0 (C_in = 1) ----
  for (int e = t; e < E_; e += NT) atomicAdd(&agg[sdst[e]], h[ssrc[e]]);
  __syncthreads();
  for (int i = t; i < XDIM; i += NT) {
    int n = i / EMB, j = i - n * EMB;
    h2s[i] = agg[n] * W0[j] + b0[j];
  }
  __syncthreads();
  for (int i = t; i < XDIM; i += NT) {
    int n = i / EMB, j = i - n * EMB;
    float g = gb0[j];
#pragma unroll
    for (int k = 0; k < EMB; ++k) g += h2s[n * EMB + k] * G0[k * EMB + j];
    h[i] = leaky(sigm(g) * h2s[i]);
  }
  __syncthreads();

  // ---- layers 1 & 2 (C = 5) ----
  for (int L = 0; L < 2; ++L) {
    const float* W  = L ? W2  : W1;
    const float* bb = L ? b2  : b1;
    const float* G  = L ? G2  : G1;
    const float* gb = L ? gb2 : gb1;
    for (int i = t; i < XDIM; i += NT) agg[i] = 0.f;
    __syncthreads();
    for (int e = t; e < E_; e += NT) {
      int s5 = ssrc[e] * EMB, d5 = sdst[e] * EMB;
#pragma unroll
      for (int j = 0; j < EMB; ++j) atomicAdd(&agg[d5 + j], h[s5 + j]);
    }
    __syncthreads();
    for (int i = t; i < XDIM; i += NT) {
      int n = i / EMB, j = i - n * EMB;
      float v = bb[j];
#pragma unroll
      for (int k = 0; k < EMB; ++k) v += agg[n * EMB + k] * W[k * EMB + j];
      h2s[i] = v;
    }
    __syncthreads();
    for (int i = t; i < XDIM; i += NT) {
      int n = i / EMB, j = i - n * EMB;
      float g = gb[j];
#pragma unroll
      for (int k = 0; k < EMB; ++k) g += h2s[n * EMB + k] * G[k * EMB + j];
      h[i] = leaky(sigm(g) * h2s[i]);
    }
    __syncthreads();
  }
  for (int i = t; i < XDIM; i += NT) xw[(size_t)b * XDIM + i] = h[i];
}

// ---------------- Kernel 2: GEMM1  h1 = leaky([x | d] @ F1 + fb1) -------------
// M=8192, K=3100, N=128. BM=32, BN=128, KT=32. 256 blocks, 256 threads.
constexpr int BM = 32, BN = 128, KT = 32;
constexpr int NCH = (KTOT + KT - 1) / KT;   // 97
constexpr int APAD = BM + 4;                // 36: breaks bank aliasing, keeps 16B align

__global__ __launch_bounds__(NT) void gemm1_kernel(
    const float* __restrict__ xw, const float* __restrict__ dd,
    const float* __restrict__ F1, const float* __restrict__ fb1,
    float* __restrict__ h1)
{
  __shared__ float At[KT * APAD];   // [kk][r]  (k-major, transposed)
  __shared__ float Bt[KT * BN];     // [kk][j]
  const int t    = threadIdx.x;
  const int row0 = blockIdx.x * BM;
  const int rg   = t >> 5;          // 0..7  -> rows rg*4..+3
  const int jg   = t & 31;          // 0..31 -> cols jg*4..+3
  const int a_kk = (t & 7) * 4;     // 0..28 step 4
  const int a_r  = t >> 3;          // 0..31
  const int a_row= row0 + a_r;
  const int b_j  = (t & 31) * 4;
  const int b_kk = t >> 5;          // 0..7

  float acc[4][4] = {{0.f,0.f,0.f,0.f},{0.f,0.f,0.f,0.f},{0.f,0.f,0.f,0.f},{0.f,0.f,0.f,0.f}};
  float4 na;
  float4 nb0, nb1, nb2, nb3;

  // K is a multiple of 4 and the x/d boundary (500) is a multiple of 4, so a
  // float4 never straddles the concat seam or the K end partially.
  auto fetch = [&](int k0) {
    int ka = k0 + a_kk;
    if (ka >= KTOT)      na = make_float4(0.f, 0.f, 0.f, 0.f);
    else if (ka < XDIM)  na = *(const float4*)(xw + (size_t)a_row * XDIM + ka);
    else                 na = *(const float4*)(dd + (size_t)a_row * DDIM + (ka - XDIM));
    int k;
    k = k0 + b_kk;      nb0 = (k < KTOT) ? *(const float4*)(F1 + (size_t)k * BN + b_j) : make_float4(0.f,0.f,0.f,0.f);
    k = k0 + b_kk + 8;  nb1 = (k < KTOT) ? *(const float4*)(F1 + (size_t)k * BN + b_j) : make_float4(0.f,0.f,0.f,0.f);
    k = k0 + b_kk + 16; nb2 = (k < KTOT) ? *(const float4*)(F1 + (size_t)k * BN + b_j) : make_float4(0.f,0.f,0.f,0.f);
    k = k0 + b_kk + 24; nb3 = (k < KTOT) ? *(const float4*)(F1 + (size_t)k * BN + b_j) : make_float4(0.f,0.f,0.f,0.f);
  };

  fetch(0);
  for (int ch = 0; ch < NCH; ++ch) {
    __syncthreads();
    At[(a_kk + 0) * APAD + a_r] = na.x;
    At[(a_kk + 1) * APAD + a_r] = na.y;
    At[(a_kk + 2) * APAD + a_r] = na.z;
    At[(a_kk + 3) * APAD + a_r] = na.w;
    *(float4*)(Bt + (b_kk +  0) * BN + b_j) = nb0;
    *(float4*)(Bt + (b_kk +  8) * BN + b_j) = nb1;
    *(float4*)(Bt + (b_kk + 16) * BN + b_j) = nb2;
    *(float4*)(Bt + (b_kk + 24) * BN + b_j) = nb3;
    __syncthreads();
    if (ch + 1 < NCH) fetch((ch + 1) * KT);   // globals in flight over compute
#pragma unroll
    for (int kk = 0; kk < KT; ++kk) {
      float4 a4 = *(const float4*)(At + kk * APAD + rg * 4);
      float4 b4 = *(const float4*)(Bt + kk * BN  + jg * 4);
      acc[0][0] += a4.x * b4.x; acc[0][1] += a4.x * b4.y; acc[0][2] += a4.x * b4.z; acc[0][3] += a4.x * b4.w;
      acc[1][0] += a4.y * b4.x; acc[1][1] += a4.y * b4.y; acc[1][2] += a4.y * b4.z; acc[1][3] += a4.y * b4.w;
      acc[2][0] += a4.z * b4.x; acc[2][1] += a4.z * b4.y; acc[2][2] += a4.z * b4.z; acc[2][3] += a4.z * b4.w;
      acc[3][0] += a4.w * b4.x; acc[3][1] += a4.w * b4.y; acc[3][2] += a4.w * b4.z; acc[3][3] += a4.w * b4.w;
    }
  }
  float4 fb = *(const float4*)(fb1 + jg * 4);
#pragma unroll
  for (int i = 0; i < 4; ++i) {
    int row = row0 + rg * 4 + i;
    float4 o;
    o.x = leaky(acc[i][0] + fb.x);
    o.y = leaky(acc[i][1] + fb.y);
    o.z = leaky(acc[i][2] + fb.z);
    o.w = leaky(acc[i][3] + fb.w);
    *(float4*)(h1 + (size_t)row * H1 + jg * 4) = o;
  }
}

// ---------------- Kernel 3: fused MLP tail F2 -> F3 -> F4(+sigmoid) ------------
constexpr int TM = 32;      // rows per block
constexpr int TP = 36;      // padded r-stride (mult of 4 -> aligned float4)

__global__ __launch_bounds__(NT) void tail_kernel(
    const float* __restrict__ h1,
    const float* __restrict__ F2, const float* __restrict__ fb2,
    const float* __restrict__ F3, const float* __restrict__ fb3,
    const float* __restrict__ F4, const float* __restrict__ fb4,
    float* __restrict__ out)
{
  __shared__ float hT [H1 * TP];   // [k][r]
  __shared__ float h2T[H2 * TP];
  __shared__ float h3T[H3 * TP];
  const int t  = threadIdx.x;
  const int b0 = blockIdx.x * TM;

  {
    int k = t & 127, rb = t >> 7;
#pragma unroll
    for (int i = 0; i < 16; ++i) {
      int r = rb + 2 * i;
      hT[k * TP + r] = h1[(size_t)(b0 + r) * H1 + k];
    }
  }
  __syncthreads();

  // phase A: h2 = leaky(h1 @ F2 + fb2)   (32 x 128)
  {
    int rg = t >> 5, jg = t & 31;
    float acc[4][4] = {{0.f,0.f,0.f,0.f},{0.f,0.f,0.f,0.f},{0.f,0.f,0.f,0.f},{0.f,0.f,0.f,0.f}};
    for (int k = 0; k < H1; ++k) {
      float4 a4 = *(const float4*)(hT + k * TP + rg * 4);
      float4 f4 = *(const float4*)(F2 + (size_t)k * H2 + jg * 4);
      acc[0][0] += a4.x * f4.x; acc[0][1] += a4.x * f4.y; acc[0][2] += a4.x * f4.z; acc[0][3] += a4.x * f4.w;
      acc[1][0] += a4.y * f4.x; acc[1][1] += a4.y * f4.y; acc[1][2] += a4.y * f4.z; acc[1][3] += a4.y * f4.w;
      acc[2][0] += a4.z * f4.x; acc[2][1] += a4.z * f4.y; acc[2][2] += a4.z * f4.z; acc[2][3] += a4.z * f4.w;
      acc[3][0] += a4.w * f4.x; acc[3][1] += a4.w * f4.y; acc[3][2] += a4.w * f4.z; acc[3][3] += a4.w * f4.w;
    }
    float4 fb = *(const float4*)(fb2 + jg * 4);
    const float fbv[4] = {fb.x, fb.y, fb.z, fb.w};
#pragma unroll
    for (int jj = 0; jj < 4; ++jj) {
      float4 o;
      o.x = leaky(acc[0][jj] + fbv[jj]);
      o.y = leaky(acc[1][jj] + fbv[jj]);
      o.z = leaky(acc[2][jj] + fbv[jj]);
      o.w = leaky(acc[3][jj] + fbv[jj]);
      *(float4*)(h2T + (jg * 4 + jj) * TP + rg * 4) = o;
    }
  }
  __syncthreads();

  // phase B: h3 = leaky(h2 @ F3 + fb3)   (32 x 64)
  {
    int rg = t >> 5, jg = t & 31;
    float acc[4][2] = {{0.f,0.f},{0.f,0.f},{0.f,0.f},{0.f,0.f}};
    for (int k = 0; k < H2; ++k) {
      float4 a4 = *(const float4*)(h2T + k * TP + rg * 4);
      float2 f2 = *(const float2*)(F3 + (size_t)k * H3 + jg * 2);
      acc[0][0] += a4.x * f2.x; acc[0][1] += a4.x * f2.y;
      acc[1][0] += a4.y * f2.x; acc[1][1] += a4.y * f2.y;
      acc[2][0] += a4.z * f2.x; acc[2][1] += a4.z * f2.y;
      acc[3][0] += a4.w * f2.x; acc[3][1] += a4.w * f2.y;
    }
#pragma unroll
    for (int jj = 0; jj < 2; ++jj) {
      float bias = fb3[jg * 2 + jj];
      float4 o;
      o.x = leaky(acc[0][jj] + bias);
      o.y = leaky(acc[1][jj] + bias);
      o.z = leaky(acc[2][jj] + bias);
      o.w = leaky(acc[3][jj] + bias);
      *(float4*)(h3T + (jg * 2 + jj) * TP + rg * 4) = o;
    }
  }
  __syncthreads();

  // phase C: out = sigmoid(h3 @ F4 + fb4)   (32 x 2)
  if (t < TM * HO) {
    int r = t >> 1, j = t & 1;
    float acc = fb4[j];
    for (int k = 0; k < H3; ++k) acc += h3T[k * TP + r] * F4[k * HO + j];
    out[(size_t)(b0 + r) * HO + j] = sigm(acc);
  }
}

// ---------------- launch ------------------------------------------------------
extern "C" void kernel_launch(void* const* d_in, const int* in_sizes, int n_in,
                              void* d_out, int out_size, void* d_ws, size_t ws_size,
                              hipStream_t stream) {
  const float* data = (const float*)d_in[0];
  const float* dmat = (const float*)d_in[1];
  const int*   src  = (const int*)d_in[2];
  const int*   dst  = (const int*)d_in[3];
  const float* W0 = (const float*)d_in[4];  const float* b0 = (const float*)d_in[5];
  const float* G0 = (const float*)d_in[6];  const float* gb0 = (const float*)d_in[7];
  const float* W1 = (const float*)d_in[8];  const float* b1 = (const float*)d_in[9];
  const float* G1 = (const float*)d_in[10]; const float* gb1 = (const float*)d_in[11];
  const float* W2 = (const float*)d_in[12]; const float* b2 = (const float*)d_in[13];
  const float* G2 = (const float*)d_in[14]; const float* gb2 = (const float*)d_in[15];
  const float* F1 = (const float*)d_in[16]; const float* fb1 = (const float*)d_in[17];
  const float* F2 = (const float*)d_in[18]; const float* fb2 = (const float*)d_in[19];
  const float* F3 = (const float*)d_in[20]; const float* fb3 = (const float*)d_in[21];
  const float* F4 = (const float*)d_in[22]; const float* fb4 = (const float*)d_in[23];
  float* out = (float*)d_out;

  float* xw = (float*)d_ws;                      // B_ * XDIM fp32  (16.4 MB)
  float* h1 = xw + (size_t)B_ * XDIM;            // B_ * H1   fp32  ( 4.2 MB)

  gnn_kernel<<<B_, NT, 0, stream>>>(data, src, dst,
                                    W0, b0, G0, gb0,
                                    W1, b1, G1, gb1,
                                    W2, b2, G2, gb2, xw);
  gemm1_kernel<<<B_ / BM, NT, 0, stream>>>(xw, dmat, F1, fb1, h1);
  tail_kernel<<<B_ / TM, NT, 0, stream>>>(h1, F2, fb2, F3, fb3, F4, fb4, out);
}

// Round 2
// 385.980 us; speedup vs baseline: 2.7496x; 2.7496x over previous
//
#include <hip/hip_runtime.h>
#include <math.h>

#define NT 256
constexpr int B_   = 8192;
constexpr int N_   = 100;
constexpr int E_   = 1600;
constexpr int EMB  = 5;
constexpr int XDIM = 500;    // N_*EMB
constexpr int DDIM = 2600;   // 50*52
constexpr int KTOT = 3100;   // XDIM + DDIM
constexpr int H1 = 128, H2 = 128, H3 = 64, HO = 2;

__device__ __forceinline__ float leaky(float v) { return v > 0.f ? v : 0.01f * v; }
__device__ __forceinline__ float sigm(float v)  { return 1.f / (1.f + __expf(-v)); }

// ---------------- Kernel 0: build CSR (dst-sorted) once per launch ------------
__global__ __launch_bounds__(NT) void csr_build(
    const int* __restrict__ src, const int* __restrict__ dst,
    int* __restrict__ off_g, int* __restrict__ lst_g)
{
  __shared__ int cnt[N_ + 1];
  __shared__ int cur[N_];
  const int t = threadIdx.x;
  if (t <= N_) cnt[t] = 0;
  __syncthreads();
  for (int e = t; e < E_; e += NT) atomicAdd(&cnt[dst[e] + 1], 1);
  __syncthreads();
  if (t == 0) {
    int s = 0;
    for (int n = 0; n <= N_; ++n) { s += cnt[n]; cnt[n] = s; }   // cnt[n] = start(n)
  }
  __syncthreads();
  if (t < N_) cur[t] = cnt[t];
  if (t <= N_) off_g[t] = cnt[t];
  __syncthreads();
  for (int e = t; e < E_; e += NT) {
    int d = dst[e];
    int p = atomicAdd(&cur[d], 1);
    lst_g[p] = src[e];
  }
}

// ---------------- Kernel 1: fused 3-layer gated RGCN, gather version ----------
// BT batches per block; node stride padded to NP=8 floats so the 5-wide
// embedding gather is ds_read_b128 + ds_read_b32 (16B-aligned at src*32B).
constexpr int BT = 4;
constexpr int NP = 8;
constexpr int HS = N_ * NP;   // 800 floats per batch plane

// weight LDS layout: [0..4] W0, [5..9] b0, [10..34] G0, [35..39] gb0,
// L1 base 40 / L2 base 100: W +0..24, b +25..29, G +30..54, gb +55..59
__global__ __launch_bounds__(NT) void gnn_kernel(
    const float* __restrict__ data,
    const int* __restrict__ off_g, const int* __restrict__ lst_g,
    const float* __restrict__ W0, const float* __restrict__ b0, const float* __restrict__ G0, const float* __restrict__ gb0,
    const float* __restrict__ W1, const float* __restrict__ b1, const float* __restrict__ G1, const float* __restrict__ gb1,
    const float* __restrict__ W2, const float* __restrict__ b2, const float* __restrict__ G2, const float* __restrict__ gb2,
    float* __restrict__ xw)
{
  __shared__ float bufA[BT][HS];
  __shared__ float bufB[BT][HS];
  __shared__ int   soff[N_ + 1];
  __shared__ int   slst[E_];
  __shared__ float wts[160];
  const int t  = threadIdx.x;
  const int b0_ = blockIdx.x * BT;

  for (int i = t; i < E_; i += NT) slst[i] = lst_g[i];
  if (t <= N_) soff[t] = off_g[t];
  if (t < 5)  { wts[t] = W0[t]; wts[5 + t] = b0[t]; wts[35 + t] = gb0[t]; }
  if (t < 25) { wts[10 + t] = G0[t];
                wts[40 + t] = W1[t]; wts[70 + t]  = G1[t];
                wts[100 + t] = W2[t]; wts[130 + t] = G2[t]; }
  if (t < 5)  { wts[65 + t] = b1[t]; wts[95 + t]  = gb1[t];
                wts[125 + t] = b2[t]; wts[155 + t] = gb2[t]; }
  // load data -> bufA[b][n] (stride 1, n<100)
  for (int i = t; i < BT * N_; i += NT) {
    int bb = i / N_, n = i - bb * N_;
    bufA[bb][n] = data[(size_t)(b0_ + bb) * N_ + n];
  }
  __syncthreads();

  // ---- Layer 0: gather(scalar) + linear : read A -> write B ----
  for (int i = t; i < BT * N_; i += NT) {
    int bb = i / N_, n = i - bb * N_;
    float a = 0.f;
    int s = soff[n], e = soff[n + 1];
    for (int q = s; q < e; ++q) a += bufA[bb][slst[q]];
    float4 o; o.x = a * wts[0] + wts[5]; o.y = a * wts[1] + wts[6];
    o.z = a * wts[2] + wts[7]; o.w = a * wts[3] + wts[8];
    *(float4*)&bufB[bb][n * NP] = o;
    bufB[bb][n * NP + 4] = a * wts[4] + wts[9];
  }
  __syncthreads();

  // gate phases (read h2 buf, write h buf) and gather+lin phases alternate.
#define GATE_PHASE(RB, WA, GOF, GBOF)                                          \
  for (int i = t; i < BT * N_; i += NT) {                                      \
    int bb = i / N_, n = i - bb * N_;                                          \
    float4 h4 = *(const float4*)&RB[bb][n * NP];                               \
    float hv[5] = {h4.x, h4.y, h4.z, h4.w, RB[bb][n * NP + 4]};                \
    float ov[5];                                                               \
    _Pragma("unroll")                                                          \
    for (int j = 0; j < 5; ++j) {                                              \
      float g = wts[(GBOF) + j];                                               \
      _Pragma("unroll")                                                        \
      for (int k = 0; k < 5; ++k) g += hv[k] * wts[(GOF) + k * 5 + j];         \
      ov[j] = leaky(sigm(g) * hv[j]);                                          \
    }                                                                          \
    float4 o; o.x = ov[0]; o.y = ov[1]; o.z = ov[2]; o.w = ov[3];              \
    *(float4*)&WA[bb][n * NP] = o;                                             \
    WA[bb][n * NP + 4] = ov[4];                                                \
  }

#define LIN_PHASE(RA, WB, WOF, BOF)                                            \
  for (int i = t; i < BT * N_; i += NT) {                                      \
    int bb = i / N_, n = i - bb * N_;                                          \
    float acc[5] = {0.f, 0.f, 0.f, 0.f, 0.f};                                  \
    int s = soff[n], e = soff[n + 1];                                          \
    for (int q = s; q < e; ++q) {                                              \
      int sp = slst[q] * NP;                                                   \
      float4 v4 = *(const float4*)&RA[bb][sp];                                 \
      acc[0] += v4.x; acc[1] += v4.y; acc[2] += v4.z; acc[3] += v4.w;          \
      acc[4] += RA[bb][sp + 4];                                                \
    }                                                                          \
    float ov[5];                                                               \
    _Pragma("unroll")                                                          \
    for (int j = 0; j < 5; ++j) {                                              \
      float v = wts[(BOF) + j];                                                \
      _Pragma("unroll")                                                        \
      for (int k = 0; k < 5; ++k) v += acc[k] * wts[(WOF) + k * 5 + j];        \
      ov[j] = v;                                                               \
    }                                                                          \
    float4 o; o.x = ov[0]; o.y = ov[1]; o.z = ov[2]; o.w = ov[3];              \
    *(float4*)&WB[bb][n * NP] = o;                                             \
    WB[bb][n * NP + 4] = ov[4];                                                \
  }

  GATE_PHASE(bufB, bufA, 10, 35)      // layer 0 gate: B -> A
  __syncthreads();
  LIN_PHASE(bufA, bufB, 40, 65)       // layer 1 gather+lin: A -> B
  __syncthreads();
  GATE_PHASE(bufB, bufA, 70, 95)      // layer 1 gate: B -> A
  __syncthreads();
  LIN_PHASE(bufA, bufB, 100, 125)     // layer 2 gather+lin: A -> B
  __syncthreads();
  GATE_PHASE(bufB, bufA, 130, 155)    // layer 2 gate: B -> A
  __syncthreads();

  // store packed [n*5+j] rows, coalesced
  for (int i = t; i < BT * XDIM; i += NT) {
    int bb = i / XDIM, r = i - bb * XDIM;
    int n = r / 5, j = r - n * 5;
    xw[(size_t)(b0_ + bb) * XDIM + r] = bufA[bb][n * NP + j];
  }
#undef GATE_PHASE
#undef LIN_PHASE
}

// ---------------- Kernel 2: GEMM1  h1 = leaky([x | d] @ F1 + fb1) -------------
constexpr int BM = 32, BN = 128, KT = 32;
constexpr int NCH = (KTOT + KT - 1) / KT;   // 97
constexpr int APAD = BM + 4;

__global__ __launch_bounds__(NT) void gemm1_kernel(
    const float* __restrict__ xw, const float* __restrict__ dd,
    const float* __restrict__ F1, const float* __restrict__ fb1,
    float* __restrict__ h1)
{
  __shared__ float At[KT * APAD];
  __shared__ float Bt[KT * BN];
  const int t    = threadIdx.x;
  const int row0 = blockIdx.x * BM;
  const int rg   = t >> 5;
  const int jg   = t & 31;
  const int a_kk = (t & 7) * 4;
  const int a_r  = t >> 3;
  const int a_row= row0 + a_r;
  const int b_j  = (t & 31) * 4;
  const int b_kk = t >> 5;

  float acc[4][4] = {{0.f,0.f,0.f,0.f},{0.f,0.f,0.f,0.f},{0.f,0.f,0.f,0.f},{0.f,0.f,0.f,0.f}};
  float4 na, nb0, nb1, nb2, nb3;

  auto fetch = [&](int k0) {
    int ka = k0 + a_kk;
    if (ka >= KTOT)      na = make_float4(0.f, 0.f, 0.f, 0.f);
    else if (ka < XDIM)  na = *(const float4*)(xw + (size_t)a_row * XDIM + ka);
    else                 na = *(const float4*)(dd + (size_t)a_row * DDIM + (ka - XDIM));
    int k;
    k = k0 + b_kk;      nb0 = (k < KTOT) ? *(const float4*)(F1 + (size_t)k * BN + b_j) : make_float4(0.f,0.f,0.f,0.f);
    k = k0 + b_kk + 8;  nb1 = (k < KTOT) ? *(const float4*)(F1 + (size_t)k * BN + b_j) : make_float4(0.f,0.f,0.f,0.f);
    k = k0 + b_kk + 16; nb2 = (k < KTOT) ? *(const float4*)(F1 + (size_t)k * BN + b_j) : make_float4(0.f,0.f,0.f,0.f);
    k = k0 + b_kk + 24; nb3 = (k < KTOT) ? *(const float4*)(F1 + (size_t)k * BN + b_j) : make_float4(0.f,0.f,0.f,0.f);
  };

  fetch(0);
  for (int ch = 0; ch < NCH; ++ch) {
    __syncthreads();
    At[(a_kk + 0) * APAD + a_r] = na.x;
    At[(a_kk + 1) * APAD + a_r] = na.y;
    At[(a_kk + 2) * APAD + a_r] = na.z;
    At[(a_kk + 3) * APAD + a_r] = na.w;
    *(float4*)(Bt + (b_kk +  0) * BN + b_j) = nb0;
    *(float4*)(Bt + (b_kk +  8) * BN + b_j) = nb1;
    *(float4*)(Bt + (b_kk + 16) * BN + b_j) = nb2;
    *(float4*)(Bt + (b_kk + 24) * BN + b_j) = nb3;
    __syncthreads();
    if (ch + 1 < NCH) fetch((ch + 1) * KT);
#pragma unroll
    for (int kk = 0; kk < KT; ++kk) {
      float4 a4 = *(const float4*)(At + kk * APAD + rg * 4);
      float4 b4 = *(const float4*)(Bt + kk * BN  + jg * 4);
      acc[0][0] += a4.x * b4.x; acc[0][1] += a4.x * b4.y; acc[0][2] += a4.x * b4.z; acc[0][3] += a4.x * b4.w;
      acc[1][0] += a4.y * b4.x; acc[1][1] += a4.y * b4.y; acc[1][2] += a4.y * b4.z; acc[1][3] += a4.y * b4.w;
      acc[2][0] += a4.z * b4.x; acc[2][1] += a4.z * b4.y; acc[2][2] += a4.z * b4.z; acc[2][3] += a4.z * b4.w;
      acc[3][0] += a4.w * b4.x; acc[3][1] += a4.w * b4.y; acc[3][2] += a4.w * b4.z; acc[3][3] += a4.w * b4.w;
    }
  }
  float4 fb = *(const float4*)(fb1 + jg * 4);
#pragma unroll
  for (int i = 0; i < 4; ++i) {
    int row = row0 + rg * 4 + i;
    float4 o;
    o.x = leaky(acc[i][0] + fb.x);
    o.y = leaky(acc[i][1] + fb.y);
    o.z = leaky(acc[i][2] + fb.z);
    o.w = leaky(acc[i][3] + fb.w);
    *(float4*)(h1 + (size_t)row * H1 + jg * 4) = o;
  }
}

// ---------------- Kernel 3: fused MLP tail F2 -> F3 -> F4(+sigmoid) ------------
constexpr int TM = 32;
constexpr int TP = 36;

__global__ __launch_bounds__(NT) void tail_kernel(
    const float* __restrict__ h1,
    const float* __restrict__ F2, const float* __restrict__ fb2,
    const float* __restrict__ F3, const float* __restrict__ fb3,
    const float* __restrict__ F4, const float* __restrict__ fb4,
    float* __restrict__ out)
{
  __shared__ float hT [H1 * TP];
  __shared__ float h2T[H2 * TP];
  __shared__ float h3T[H3 * TP];
  const int t  = threadIdx.x;
  const int b0 = blockIdx.x * TM;

  {
    int k = t & 127, rb = t >> 7;
#pragma unroll
    for (int i = 0; i < 16; ++i) {
      int r = rb + 2 * i;
      hT[k * TP + r] = h1[(size_t)(b0 + r) * H1 + k];
    }
  }
  __syncthreads();

  {
    int rg = t >> 5, jg = t & 31;
    float acc[4][4] = {{0.f,0.f,0.f,0.f},{0.f,0.f,0.f,0.f},{0.f,0.f,0.f,0.f},{0.f,0.f,0.f,0.f}};
    for (int k = 0; k < H1; ++k) {
      float4 a4 = *(const float4*)(hT + k * TP + rg * 4);
      float4 f4 = *(const float4*)(F2 + (size_t)k * H2 + jg * 4);
      acc[0][0] += a4.x * f4.x; acc[0][1] += a4.x * f4.y; acc[0][2] += a4.x * f4.z; acc[0][3] += a4.x * f4.w;
      acc[1][0] += a4.y * f4.x; acc[1][1] += a4.y * f4.y; acc[1][2] += a4.y * f4.z; acc[1][3] += a4.y * f4.w;
      acc[2][0] += a4.z * f4.x; acc[2][1] += a4.z * f4.y; acc[2][2] += a4.z * f4.z; acc[2][3] += a4.z * f4.w;
      acc[3][0] += a4.w * f4.x; acc[3][1] += a4.w * f4.y; acc[3][2] += a4.w * f4.z; acc[3][3] += a4.w * f4.w;
    }
    float4 fb = *(const float4*)(fb2 + jg * 4);
    const float fbv[4] = {fb.x, fb.y, fb.z, fb.w};
#pragma unroll
    for (int jj = 0; jj < 4; ++jj) {
      float4 o;
      o.x = leaky(acc[0][jj] + fbv[jj]);
      o.y = leaky(acc[1][jj] + fbv[jj]);
      o.z = leaky(acc[2][jj] + fbv[jj]);
      o.w = leaky(acc[3][jj] + fbv[jj]);
      *(float4*)(h2T + (jg * 4 + jj) * TP + rg * 4) = o;
    }
  }
  __syncthreads();

  {
    int rg = t >> 5, jg = t & 31;
    float acc[4][2] = {{0.f,0.f},{0.f,0.f},{0.f,0.f},{0.f,0.f}};
    for (int k = 0; k < H2; ++k) {
      float4 a4 = *(const float4*)(h2T + k * TP + rg * 4);
      float2 f2 = *(const float2*)(F3 + (size_t)k * H3 + jg * 2);
      acc[0][0] += a4.x * f2.x; acc[0][1] += a4.x * f2.y;
      acc[1][0] += a4.y * f2.x; acc[1][1] += a4.y * f2.y;
      acc[2][0] += a4.z * f2.x; acc[2][1] += a4.z * f2.y;
      acc[3][0] += a4.w * f2.x; acc[3][1] += a4.w * f2.y;
    }
#pragma unroll
    for (int jj = 0; jj < 2; ++jj) {
      float bias = fb3[jg * 2 + jj];
      float4 o;
      o.x = leaky(acc[0][jj] + bias);
      o.y = leaky(acc[1][jj] + bias);
      o.z = leaky(acc[2][jj] + bias);
      o.w = leaky(acc[3][jj] + bias);
      *(float4*)(h3T + (jg * 2 + jj) * TP + rg * 4) = o;
    }
  }
  __syncthreads();

  if (t < TM * HO) {
    int r = t >> 1, j = t & 1;
    float acc = fb4[j];
    for (int k = 0; k < H3; ++k) acc += h3T[k * TP + r] * F4[k * HO + j];
    out[(size_t)(b0 + r) * HO + j] = sigm(acc);
  }
}

// ---------------- launch ------------------------------------------------------
extern "C" void kernel_launch(void* const* d_in, const int* in_sizes, int n_in,
                              void* d_out, int out_size, void* d_ws, size_t ws_size,
                              hipStream_t stream) {
  const float* data = (const float*)d_in[0];
  const float* dmat = (const float*)d_in[1];
  const int*   src  = (const int*)d_in[2];
  const int*   dst  = (const int*)d_in[3];
  const float* W0 = (const float*)d_in[4];  const float* b0 = (const float*)d_in[5];
  const float* G0 = (const float*)d_in[6];  const float* gb0 = (const float*)d_in[7];
  const float* W1 = (const float*)d_in[8];  const float* b1 = (const float*)d_in[9];
  const float* G1 = (const float*)d_in[10]; const float* gb1 = (const float*)d_in[11];
  const float* W2 = (const float*)d_in[12]; const float* b2 = (const float*)d_in[13];
  const float* G2 = (const float*)d_in[14]; const float* gb2 = (const float*)d_in[15];
  const float* F1 = (const float*)d_in[16]; const float* fb1 = (const float*)d_in[17];
  const float* F2 = (const float*)d_in[18]; const float* fb2 = (const float*)d_in[19];
  const float* F3 = (const float*)d_in[20]; const float* fb3 = (const float*)d_in[21];
  const float* F4 = (const float*)d_in[22]; const float* fb4 = (const float*)d_in[23];
  float* out = (float*)d_out;

  float* xw = (float*)d_ws;                      // B_ * XDIM fp32
  float* h1 = xw + (size_t)B_ * XDIM;            // B_ * H1   fp32
  // CSR overlaid on h1 region: csr_build/gnn use it BEFORE gemm1 writes h1
  // (stream-ordered, so no race).
  int* off_g = (int*)h1;                         // 101 ints
  int* lst_g = off_g + 128;                      // 1600 ints

  csr_build<<<1, NT, 0, stream>>>(src, dst, off_g, lst_g);
  gnn_kernel<<<B_ / BT, NT, 0, stream>>>(data, off_g, lst_g,
                                         W0, b0, G0, gb0,
                                         W1, b1, G1, gb1,
                                         W2, b2, G2, gb2, xw);
  gemm1_kernel<<<B_ / BM, NT, 0, stream>>>(xw, dmat, F1, fb1, h1);
  tail_kernel<<<B_ / TM, NT, 0, stream>>>(h1, F2, fb2, F3, fb3, F4, fb4, out);
}

// Round 4
// 312.405 us; speedup vs baseline: 3.3971x; 1.2355x over previous
//
#include <hip/hip_runtime.h>
#include <math.h>

#define NT 256
constexpr int B_   = 8192;
constexpr int N_   = 100;
constexpr int E_   = 1600;
constexpr int EMB  = 5;
constexpr int XDIM = 500;    // N_*EMB
constexpr int DDIM = 2600;   // 50*52
constexpr int KTOT = 3100;   // XDIM + DDIM
constexpr int KPAD = 3136;   // 49*64, zero-padded K for F1T
constexpr int H1 = 128, H2 = 128, H3 = 64, HO = 2;

typedef short short8 __attribute__((ext_vector_type(8)));
typedef float f32x4  __attribute__((ext_vector_type(4)));

__device__ __forceinline__ float leaky(float v) { return v > 0.f ? v : 0.01f * v; }
__device__ __forceinline__ float sigm(float v)  { return 1.f / (1.f + __expf(-v)); }
__device__ __forceinline__ unsigned short f2bf(float f) {   // RNE fp32->bf16
  unsigned int x = __float_as_uint(f);
  return (unsigned short)((x + 0x7fffu + ((x >> 16) & 1u)) >> 16);
}

// ---------------- Kernel A: build CSR (dst-sorted) ----------------------------
__global__ __launch_bounds__(NT) void csr_build(
    const int* __restrict__ src, const int* __restrict__ dst,
    int* __restrict__ off_g, int* __restrict__ lst_g)
{
  __shared__ int cnt[N_ + 1];
  __shared__ int cur[N_];
  const int t = threadIdx.x;
  if (t <= N_) cnt[t] = 0;
  __syncthreads();
  for (int e = t; e < E_; e += NT) atomicAdd(&cnt[dst[e] + 1], 1);
  __syncthreads();
  if (t == 0) {
    int s = 0;
    for (int n = 0; n <= N_; ++n) { s += cnt[n]; cnt[n] = s; }
  }
  __syncthreads();
  if (t < N_) cur[t] = cnt[t];
  if (t <= N_) off_g[t] = cnt[t];
  __syncthreads();
  for (int e = t; e < E_; e += NT) {
    int d = dst[e];
    int p = atomicAdd(&cur[d], 1);
    lst_g[p] = src[e];
  }
}

// ---------------- Kernel B: prep transposed bf16 weights ----------------------
__global__ __launch_bounds__(NT) void prep_kernel(
    const float* __restrict__ F1, const float* __restrict__ F2, const float* __restrict__ F3,
    unsigned short* __restrict__ F1T, unsigned short* __restrict__ F2T, unsigned short* __restrict__ F3T)
{
  const int b = blockIdx.x, t = threadIdx.x;
  if (b < 128) {
    for (int k = t; k < KPAD; k += NT)
      F1T[(size_t)b * KPAD + k] = (k < KTOT) ? f2bf(F1[(size_t)k * H1 + b]) : 0;
  } else if (b < 256) {
    int n = b - 128;
    if (t < 128) F2T[n * 128 + t] = f2bf(F2[(size_t)t * H2 + n]);
  } else {
    int n = b - 256;
    if (n < 64 && t < 128) F3T[n * 128 + t] = f2bf(F3[(size_t)t * H3 + n]);
  }
}

// ---------------- Kernel C: fused 3-layer gated RGCN (gather) -----------------
constexpr int BT = 4;
constexpr int NP = 8;
constexpr int HS = N_ * NP;

__global__ __launch_bounds__(NT) void gnn_kernel(
    const float* __restrict__ data,
    const int* __restrict__ off_g, const int* __restrict__ lst_g,
    const float* __restrict__ W0, const float* __restrict__ b0, const float* __restrict__ G0, const float* __restrict__ gb0,
    const float* __restrict__ W1, const float* __restrict__ b1, const float* __restrict__ G1, const float* __restrict__ gb1,
    const float* __restrict__ W2, const float* __restrict__ b2, const float* __restrict__ G2, const float* __restrict__ gb2,
    unsigned short* __restrict__ xw)
{
  __shared__ float bufA[BT][HS];
  __shared__ float bufB[BT][HS];
  __shared__ int   soff[N_ + 1];
  __shared__ int   slst[E_];
  __shared__ float wts[160];
  const int t  = threadIdx.x;
  const int b0_ = blockIdx.x * BT;

  for (int i = t; i < E_; i += NT) slst[i] = lst_g[i];
  if (t <= N_) soff[t] = off_g[t];
  if (t < 5)  { wts[t] = W0[t]; wts[5 + t] = b0[t]; wts[35 + t] = gb0[t]; }
  if (t < 25) { wts[10 + t] = G0[t];
                wts[40 + t] = W1[t]; wts[70 + t]  = G1[t];
                wts[100 + t] = W2[t]; wts[130 + t] = G2[t]; }
  if (t < 5)  { wts[65 + t] = b1[t]; wts[95 + t]  = gb1[t];
                wts[125 + t] = b2[t]; wts[155 + t] = gb2[t]; }
  for (int i = t; i < BT * N_; i += NT) {
    int bb = i / N_, n = i - bb * N_;
    bufA[bb][n] = data[(size_t)(b0_ + bb) * N_ + n];
  }
  __syncthreads();

  for (int i = t; i < BT * N_; i += NT) {
    int bb = i / N_, n = i - bb * N_;
    float a = 0.f;
    int s = soff[n], e = soff[n + 1];
    for (int q = s; q < e; ++q) a += bufA[bb][slst[q]];
    float4 o; o.x = a * wts[0] + wts[5]; o.y = a * wts[1] + wts[6];
    o.z = a * wts[2] + wts[7]; o.w = a * wts[3] + wts[8];
    *(float4*)&bufB[bb][n * NP] = o;
    bufB[bb][n * NP + 4] = a * wts[4] + wts[9];
  }
  __syncthreads();

#define GATE_PHASE(RB, WA, GOF, GBOF)                                          \
  for (int i = t; i < BT * N_; i += NT) {                                      \
    int bb = i / N_, n = i - bb * N_;                                          \
    float4 h4 = *(const float4*)&RB[bb][n * NP];                               \
    float hv[5] = {h4.x, h4.y, h4.z, h4.w, RB[bb][n * NP + 4]};                \
    float ov[5];                                                               \
    _Pragma("unroll")                                                          \
    for (int j = 0; j < 5; ++j) {                                              \
      float g = wts[(GBOF) + j];                                               \
      _Pragma("unroll")                                                        \
      for (int k = 0; k < 5; ++k) g += hv[k] * wts[(GOF) + k * 5 + j];         \
      ov[j] = leaky(sigm(g) * hv[j]);                                          \
    }                                                                          \
    float4 o; o.x = ov[0]; o.y = ov[1]; o.z = ov[2]; o.w = ov[3];              \
    *(float4*)&WA[bb][n * NP] = o;                                             \
    WA[bb][n * NP + 4] = ov[4];                                                \
  }

#define LIN_PHASE(RA, WB, WOF, BOF)                                            \
  for (int i = t; i < BT * N_; i += NT) {                                      \
    int bb = i / N_, n = i - bb * N_;                                          \
    float acc[5] = {0.f, 0.f, 0.f, 0.f, 0.f};                                  \
    int s = soff[n], e = soff[n + 1];                                          \
    for (int q = s; q < e; ++q) {                                              \
      int sp = slst[q] * NP;                                                   \
      float4 v4 = *(const float4*)&RA[bb][sp];                                 \
      acc[0] += v4.x; acc[1] += v4.y; acc[2] += v4.z; acc[3] += v4.w;          \
      acc[4] += RA[bb][sp + 4];                                                \
    }                                                                          \
    float ov[5];                                                               \
    _Pragma("unroll")                                                          \
    for (int j = 0; j < 5; ++j) {                                              \
      float v = wts[(BOF) + j];                                                \
      _Pragma("unroll")                                                        \
      for (int k = 0; k < 5; ++k) v += acc[k] * wts[(WOF) + k * 5 + j];        \
      ov[j] = v;                                                               \
    }                                                                          \
    float4 o; o.x = ov[0]; o.y = ov[1]; o.z = ov[2]; o.w = ov[3];              \
    *(float4*)&WB[bb][n * NP] = o;                                             \
    WB[bb][n * NP + 4] = ov[4];                                                \
  }

  GATE_PHASE(bufB, bufA, 10, 35)
  __syncthreads();
  LIN_PHASE(bufA, bufB, 40, 65)
  __syncthreads();
  GATE_PHASE(bufB, bufA, 70, 95)
  __syncthreads();
  LIN_PHASE(bufA, bufB, 100, 125)
  __syncthreads();
  GATE_PHASE(bufB, bufA, 130, 155)
  __syncthreads();

  for (int i = t; i < BT * XDIM; i += NT) {
    int bb = i / XDIM, r = i - bb * XDIM;
    int n = r / 5, j = r - n * 5;
    xw[(size_t)(b0_ + bb) * XDIM + r] = f2bf(bufA[bb][n * NP + j]);
  }
#undef GATE_PHASE
#undef LIN_PHASE
}

// ---------------- Kernel D: MFMA GEMM1 + fused MLP tail -----------------------
constexpr int MB = 16;
constexpr int KC = 64;
constexpr int NCHUNK = KPAD / KC;   // 49
constexpr int LST = 72;             // main-loop LDS row stride (bf16 units)
constexpr int EST = 136;            // epilogue LDS row stride (128+8)
constexpr int ARENA = 60928;

__global__ __launch_bounds__(NT) void mlp_kernel(
    const unsigned short* __restrict__ xw, const float* __restrict__ dd,
    const unsigned short* __restrict__ F1T, const float* __restrict__ fb1,
    const unsigned short* __restrict__ F2T, const float* __restrict__ fb2,
    const unsigned short* __restrict__ F3T, const float* __restrict__ fb3,
    const float* __restrict__ F4, const float* __restrict__ fb4,
    float* __restrict__ out)
{
  __shared__ __attribute__((aligned(16))) char arena[ARENA];
  unsigned short* At = (unsigned short*)(arena);
  unsigned short* Bt = (unsigned short*)(arena + 2304);

  const int t    = threadIdx.x;
  const int row0 = blockIdx.x * MB;
  const int lane = t & 63;
  const int w    = t >> 6;          // wave id: cols w*32..w*32+31
  const int quad = lane >> 4;
  const int ln   = lane & 15;

  const int a_row = t >> 4;
  const int a_k4  = (t & 15) * 4;
  const size_t a_grow = (size_t)(row0 + a_row);
  const int b_n = t & 127;
  const int b_h = (t >> 7) * 32;

  uint2 pa;
  uint4 pb0, pb1, pb2, pb3;

  auto fetch = [&](int c) {
    int k0 = c * KC;
    int ka = k0 + a_k4;
    if (ka < XDIM) {
      pa = *(const uint2*)(xw + a_grow * XDIM + ka);
    } else if (ka < KTOT) {
      float4 f = *(const float4*)(dd + a_grow * DDIM + (ka - XDIM));
      pa.x = (unsigned)f2bf(f.x) | ((unsigned)f2bf(f.y) << 16);
      pa.y = (unsigned)f2bf(f.z) | ((unsigned)f2bf(f.w) << 16);
    } else { pa.x = 0u; pa.y = 0u; }
    const unsigned short* bp = F1T + (size_t)b_n * KPAD + k0 + b_h;
    pb0 = ((const uint4*)bp)[0];
    pb1 = ((const uint4*)bp)[1];
    pb2 = ((const uint4*)bp)[2];
    pb3 = ((const uint4*)bp)[3];
  };

  f32x4 acc0 = {0.f, 0.f, 0.f, 0.f};
  f32x4 acc1 = {0.f, 0.f, 0.f, 0.f};

  fetch(0);
  for (int c = 0; c < NCHUNK; ++c) {
    __syncthreads();
    *(uint2*)(At + a_row * LST + a_k4) = pa;
    {
      unsigned short* bq = Bt + b_n * LST + b_h;
      ((uint4*)bq)[0] = pb0; ((uint4*)bq)[1] = pb1;
      ((uint4*)bq)[2] = pb2; ((uint4*)bq)[3] = pb3;
    }
    __syncthreads();
    if (c + 1 < NCHUNK) fetch(c + 1);
#pragma unroll
    for (int s = 0; s < 2; ++s) {
      short8 af = *(const short8*)(At + ln * LST + s * 32 + quad * 8);
      short8 b0f = *(const short8*)(Bt + (w * 32      + ln) * LST + s * 32 + quad * 8);
      short8 b1f = *(const short8*)(Bt + (w * 32 + 16 + ln) * LST + s * 32 + quad * 8);
      acc0 = __builtin_amdgcn_mfma_f32_16x16x32_bf16(af, b0f, acc0, 0, 0, 0);
      acc1 = __builtin_amdgcn_mfma_f32_16x16x32_bf16(af, b1f, acc1, 0, 0, 0);
    }
  }
  __syncthreads();   // main-loop LDS dead; arena is reused below

  unsigned short* sF2 = (unsigned short*)(arena);
  unsigned short* sF3 = (unsigned short*)(arena + 34816);
  unsigned short* sH  = (unsigned short*)(arena + 52224);
  float*          sh3 = (float*)(arena + 56576);

  // stage F2T -> sF2: thread t copies 64 bf16 (8 x uint4): row t>>1, half t&1
  {
    const uint4* sp = (const uint4*)(F2T + (t >> 1) * H2 + (t & 1) * 64);
    uint4*       dp = (uint4*)(sF2 + (t >> 1) * EST + (t & 1) * 64);
#pragma unroll
    for (int i = 0; i < 8; ++i) dp[i] = sp[i];
  }
  // stage F3T -> sF3: thread t copies 32 bf16 (4 x uint4): row t>>2, quarter t&3
  {
    const uint4* sp = (const uint4*)(F3T + (t >> 2) * H2 + (t & 3) * 32);
    uint4*       dp = (uint4*)(sF3 + (t >> 2) * EST + (t & 3) * 32);
#pragma unroll
    for (int i = 0; i < 4; ++i) dp[i] = sp[i];
  }
  // h1 = leaky(acc + fb1) -> sH [m][col] bf16 (C-layout -> A-layout round-trip)
  {
    int col0 = w * 32 + ln;
    float bb0 = fb1[col0], bb1 = fb1[col0 + 16];
#pragma unroll
    for (int r = 0; r < 4; ++r) {
      int m = quad * 4 + r;
      sH[m * EST + col0]      = f2bf(leaky(acc0[r] + bb0));
      sH[m * EST + col0 + 16] = f2bf(leaky(acc1[r] + bb1));
    }
  }
  __syncthreads();

  // h2 = leaky(h1 @ F2 + fb2): K=128, wave w -> cols w*32 + {0,16}
  f32x4 a20 = {0.f, 0.f, 0.f, 0.f};
  f32x4 a21 = {0.f, 0.f, 0.f, 0.f};
#pragma unroll
  for (int s = 0; s < 4; ++s) {
    short8 af  = *(const short8*)(sH + ln * EST + s * 32 + quad * 8);
    short8 b0f = *(const short8*)(sF2 + (w * 32      + ln) * EST + s * 32 + quad * 8);
    short8 b1f = *(const short8*)(sF2 + (w * 32 + 16 + ln) * EST + s * 32 + quad * 8);
    a20 = __builtin_amdgcn_mfma_f32_16x16x32_bf16(af, b0f, a20, 0, 0, 0);
    a21 = __builtin_amdgcn_mfma_f32_16x16x32_bf16(af, b1f, a21, 0, 0, 0);
  }
  __syncthreads();   // done reading sH; overwrite with h2
  {
    int col0 = w * 32 + ln;
    float bb0 = fb2[col0], bb1 = fb2[col0 + 16];
#pragma unroll
    for (int r = 0; r < 4; ++r) {
      int m = quad * 4 + r;
      sH[m * EST + col0]      = f2bf(leaky(a20[r] + bb0));
      sH[m * EST + col0 + 16] = f2bf(leaky(a21[r] + bb1));
    }
  }
  __syncthreads();

  // h3 = leaky(h2 @ F3 + fb3): K=128, N=64, wave w -> cols w*16..+15
  f32x4 a3 = {0.f, 0.f, 0.f, 0.f};
#pragma unroll
  for (int s = 0; s < 4; ++s) {
    short8 af = *(const short8*)(sH + ln * EST + s * 32 + quad * 8);
    short8 bf = *(const short8*)(sF3 + (w * 16 + ln) * EST + s * 32 + quad * 8);
    a3 = __builtin_amdgcn_mfma_f32_16x16x32_bf16(af, bf, a3, 0, 0, 0);
  }
  {
    int col = w * 16 + ln;
    float bb = fb3[col];
#pragma unroll
    for (int r = 0; r < 4; ++r)
      sh3[(quad * 4 + r) * 68 + col] = leaky(a3[r] + bb);
  }
  __syncthreads();

  // out = sigmoid(h3 @ F4 + fb4): 16 rows x 2
  if (t < MB * HO) {
    int m = t >> 1, j = t & 1;
    float a = fb4[j];
#pragma unroll 8
    for (int k = 0; k < H3; ++k) a += sh3[m * 68 + k] * F4[k * HO + j];
    out[(size_t)(row0 + m) * HO + j] = sigm(a);
  }
}

// ---------------- launch ------------------------------------------------------
extern "C" void kernel_launch(void* const* d_in, const int* in_sizes, int n_in,
                              void* d_out, int out_size, void* d_ws, size_t ws_size,
                              hipStream_t stream) {
  const float* data = (const float*)d_in[0];
  const float* dmat = (const float*)d_in[1];
  const int*   src  = (const int*)d_in[2];
  const int*   dst  = (const int*)d_in[3];
  const float* W0 = (const float*)d_in[4];  const float* b0 = (const float*)d_in[5];
  const float* G0 = (const float*)d_in[6];  const float* gb0 = (const float*)d_in[7];
  const float* W1 = (const float*)d_in[8];  const float* b1 = (const float*)d_in[9];
  const float* G1 = (const float*)d_in[10]; const float* gb1 = (const float*)d_in[11];
  const float* W2 = (const float*)d_in[12]; const float* b2 = (const float*)d_in[13];
  const float* G2 = (const float*)d_in[14]; const float* gb2 = (const float*)d_in[15];
  const float* F1 = (const float*)d_in[16]; const float* fb1 = (const float*)d_in[17];
  const float* F2 = (const float*)d_in[18]; const float* fb2 = (const float*)d_in[19];
  const float* F3 = (const float*)d_in[20]; const float* fb3 = (const float*)d_in[21];
  const float* F4 = (const float*)d_in[22]; const float* fb4 = (const float*)d_in[23];
  float* out = (float*)d_out;

  unsigned short* xw  = (unsigned short*)d_ws;          // 8192*500 bf16
  unsigned short* F1T = xw + (size_t)B_ * XDIM;         // 128*3136
  unsigned short* F2T = F1T + 128 * KPAD;               // 128*128
  unsigned short* F3T = F2T + 128 * 128;                // 64*128
  int* off_g = (int*)(F3T + 64 * 128);                  // 101 (pad 104)
  int* lst_g = off_g + 104;                             // 1600

  csr_build<<<1, NT, 0, stream>>>(src, dst, off_g, lst_g);
  prep_kernel<<<320, NT, 0, stream>>>(F1, F2, F3, F1T, F2T, F3T);
  gnn_kernel<<<B_ / BT, NT, 0, stream>>>(data, off_g, lst_g,
                                         W0, b0, G0, gb0,
                                         W1, b1, G1, gb1,
                                         W2, b2, G2, gb2, xw);
  mlp_kernel<<<B_ / MB, NT, 0, stream>>>(xw, dmat, F1T, fb1, F2T, fb2,
                                         F3T, fb3, F4, fb4, out);
}